// Round 1
// baseline (154.510 us; speedup 1.0000x reference)
//
#include <hip/hip_runtime.h>

// BoxCrossCategoryLoss: provably constant-zero output.
//
// Proof sketch (see round-0 analysis):
//   cx = clsx + 4*flag, cy = clsy + 4*flag, cz = clsz + 4*flag  (SAME flag),
//   so (cx>>2) == (cy>>2) == (cz>>2) for every element.
//   Every triple in LOSS_RECIPE and NEG_LOSS_RECIPE has mixed high bits
//   ((xy>>2, yz>>2, xz>>2) never all-equal), so every mask m is identically
//   false. Positive terms sum to 0; negative terms have count==0 so the
//   jnp.where selects 0. Therefore loss == 0.0f for ALL inputs.
//
// The kernel only needs to write the constant to d_out (which is re-poisoned
// to 0xAA before every timed launch).

__global__ void BoxCrossCategoryLoss_write_zero(float* __restrict__ out) {
    if (threadIdx.x == 0) {
        out[0] = 0.0f;
    }
}

extern "C" void kernel_launch(void* const* d_in, const int* in_sizes, int n_in,
                              void* d_out, int out_size, void* d_ws, size_t ws_size,
                              hipStream_t stream) {
    (void)d_in; (void)in_sizes; (void)n_in; (void)d_ws; (void)ws_size; (void)out_size;
    BoxCrossCategoryLoss_write_zero<<<1, 64, 0, stream>>>((float*)d_out);
}